// Round 5
// baseline (272.591 us; speedup 1.0000x reference)
//
#include <hip/hip_runtime.h>
#include <hip/hip_bf16.h>

#define NN 50000
#define NE 800000
#define HID 128
#define APITCH 136        // node-gemm A-tile pitch in bf16 elems (=68 dwords)

typedef float f32x4 __attribute__((ext_vector_type(4)));
typedef short s16x8 __attribute__((ext_vector_type(8)));
typedef unsigned int u32;

__device__ __forceinline__ unsigned short f2bf(float x) {   // RNE
    u32 u = __float_as_uint(x);
    u32 r = (u + 0x7FFFu + ((u >> 16) & 1u)) >> 16;
    return (unsigned short)r;
}
__device__ __forceinline__ float silu_f(float v) {          // no IEEE divide
    float e = __expf(-v);
    return v * __builtin_amdgcn_rcpf(1.f + e);
}
// pack two f32 -> dword (bf16 lo | bf16 hi<<16), truncation
__device__ __forceinline__ u32 pack2bf(float lo, float hi) {
    return __builtin_amdgcn_perm(__float_as_uint(hi), __float_as_uint(lo), 0x07060302u);
}
__device__ __forceinline__ u32 fuse_silu_pack(u32 a, u32 b, float ea, float wlo, float whi) {
    float xlo = __uint_as_float(a << 16) + __uint_as_float(b << 16) + ea * wlo;
    float xhi = __uint_as_float(a & 0xFFFF0000u) + __uint_as_float(b & 0xFFFF0000u) + ea * whi;
    return pack2bf(silu_f(xlo), silu_f(xhi));
}

// prep: W1 rows 0..255 -> W1p bf16 [32 kblk][128 n][8 kin]
//       W2 -> W2p bf16 [16 kblk][128 n][8 kin] with sigma k-permutation
//       (p=kblk*8+kin, t=p>>1, srow=32*(t>>4)+(t&15)+16*(p&1)) -- matches the
//       sigma-paired x1 dword layout (verified R3/R4).
//       Also zeros d_out (replaces the hipMemsetAsync dispatch).
__global__ void prep_full(const float* __restrict__ W1, const float* __restrict__ W2,
                          unsigned short* __restrict__ W1p, unsigned short* __restrict__ W2p,
                          float4* __restrict__ outz, int out_q) {
    int idx = blockIdx.x * blockDim.x + threadIdx.x;
    const int n1 = 32 * 128 * 8;
    const int n2 = 16 * 128 * 8;
    if (idx < n1) {
        int kblk = idx >> 10;
        int rem  = idx & 1023;
        int n    = rem >> 3;
        int kin  = rem & 7;
        W1p[idx] = f2bf(W1[(kblk * 8 + kin) * HID + n]);
    } else if (idx < n1 + n2) {
        int jj   = idx - n1;
        int kblk = jj >> 10;
        int rem  = jj & 1023;
        int n    = rem >> 3;
        int kin  = rem & 7;
        int p    = kblk * 8 + kin;
        int tt   = p >> 1;
        int srow = 32 * (tt >> 4) + (tt & 15) + 16 * (p & 1);
        W2p[jj] = f2bf(W2[srow * HID + n]);
    } else {
        int z = idx - (n1 + n2);
        if (z < out_q) outz[z] = float4{0.f, 0.f, 0.f, 0.f};
    }
}

// node_gemm: Pa[n] = h[n] @ W1[0:128,:] + b1, Pb[n] = h[n] @ W1[128:256,:]
// stored sigma-paired bf16, 64 dwords/row: dword d holds cols (32*(d>>4)+(d&15), +16).
__global__ __launch_bounds__(256) void node_gemm(const float* __restrict__ h,
                                                 const unsigned short* __restrict__ W1p,
                                                 const float* __restrict__ b1,
                                                 u32* __restrict__ Pa, u32* __restrict__ Pb) {
    __shared__ unsigned short s_a[64 * APITCH];   // 17408 B
    const int tid = threadIdx.x;
    const int m0  = blockIdx.x * 64;

    #pragma unroll
    for (int it = 0; it < 8; ++it) {
        int chunk = it * 256 + tid;
        int r  = chunk >> 5;
        int cc = chunk & 31;
        int row = m0 + r;
        float4 v = {0.f, 0.f, 0.f, 0.f};
        if (row < NN) v = *(const float4*)(h + (size_t)row * HID + cc * 4);
        uint2 pk;
        pk.x = ((u32)f2bf(v.x)) | ((u32)f2bf(v.y) << 16);
        pk.y = ((u32)f2bf(v.z)) | ((u32)f2bf(v.w) << 16);
        *(uint2*)&s_a[r * APITCH + cc * 4] = pk;
    }
    __syncthreads();

    const int lane = tid & 63;
    const int w    = tid >> 6;
    const int q    = lane >> 4;
    const int c16  = lane & 15;
    const int n0   = w * 32 + c16;

    f32x4 accA[4][2], accB[4][2];
    #pragma unroll
    for (int mt = 0; mt < 4; ++mt) {
        accA[mt][0] = f32x4{0.f,0.f,0.f,0.f}; accA[mt][1] = f32x4{0.f,0.f,0.f,0.f};
        accB[mt][0] = f32x4{0.f,0.f,0.f,0.f}; accB[mt][1] = f32x4{0.f,0.f,0.f,0.f};
    }
    #pragma unroll
    for (int ks = 0; ks < 4; ++ks) {
        s16x8 afr[4];
        #pragma unroll
        for (int mt = 0; mt < 4; ++mt)
            afr[mt] = *(const s16x8*)&s_a[(mt * 16 + c16) * APITCH + ks * 32 + q * 8];
        int ka = ks * 4 + q;
        int kb = 16 + ks * 4 + q;
        s16x8 ba0 = *(const s16x8*)(W1p + (size_t)(ka * HID + n0) * 8);
        s16x8 ba1 = *(const s16x8*)(W1p + (size_t)(ka * HID + n0 + 16) * 8);
        s16x8 bb0 = *(const s16x8*)(W1p + (size_t)(kb * HID + n0) * 8);
        s16x8 bb1 = *(const s16x8*)(W1p + (size_t)(kb * HID + n0 + 16) * 8);
        #pragma unroll
        for (int mt = 0; mt < 4; ++mt) {
            accA[mt][0] = __builtin_amdgcn_mfma_f32_16x16x32_bf16(afr[mt], ba0, accA[mt][0], 0, 0, 0);
            accA[mt][1] = __builtin_amdgcn_mfma_f32_16x16x32_bf16(afr[mt], ba1, accA[mt][1], 0, 0, 0);
            accB[mt][0] = __builtin_amdgcn_mfma_f32_16x16x32_bf16(afr[mt], bb0, accB[mt][0], 0, 0, 0);
            accB[mt][1] = __builtin_amdgcn_mfma_f32_16x16x32_bf16(afr[mt], bb1, accB[mt][1], 0, 0, 0);
        }
    }
    float b1lo = b1[n0], b1hi = b1[n0 + 16];
    const int d = w * 16 + c16;
    #pragma unroll
    for (int mt = 0; mt < 4; ++mt) {
        #pragma unroll
        for (int r = 0; r < 4; ++r) {
            int m = mt * 16 + q * 4 + r;
            int row = m0 + m;
            if (row < NN) {
                Pa[(size_t)row * 64 + d] = pack2bf(accA[mt][0][r] + b1lo, accA[mt][1][r] + b1hi);
                Pb[(size_t)row * 64 + d] = pack2bf(accB[mt][0][r], accB[mt][1][r]);
            }
        }
    }
}

// edge_main: barrier-free, LDS-free. Wave w of each block owns edges
// [blockIdx*64 + w*16, +16). Gather layout == MFMA A-fragment layout:
// lane(q,c16) holds row c16's sigma dwords {q*4 + j*16 + i}, which is exactly
// the A-frag (ks=j, q) the layer-2 MFMA needs. No __syncthreads anywhere.
__global__ __launch_bounds__(256) void edge_main(
        const u32* __restrict__ Pa, const u32* __restrict__ Pb,
        const int* __restrict__ edge_index,
        const float* __restrict__ coord_diff, const float* __restrict__ edge_attr,
        const float* __restrict__ edge_mask,
        const unsigned short* __restrict__ W2p,
        const float* __restrict__ W1, const float* __restrict__ b2,
        const float* __restrict__ W3, float* __restrict__ agg) {
    const int tid  = threadIdx.x;
    const int lane = tid & 63;
    const int w    = tid >> 6;
    const int q    = lane >> 4;
    const int c16  = lane & 15;
    const int e0   = blockIdx.x * 64 + w * 16;   // this wave's edge band

    // loop-invariant layer-3 constants for this lane's columns n = nt*16 + c16
    float b2v[8], w3v[8];
    #pragma unroll
    for (int nt = 0; nt < 8; ++nt) {
        b2v[nt] = b2[nt * 16 + c16];
        w3v[nt] = W3[nt * 16 + c16];
    }

    // indices for gather edge m = c16 (16-fold redundant across q groups; L1 hits)
    const int   em = e0 + c16;
    const int   ir = edge_index[em];
    const int   ic = edge_index[NE + em];
    const float ea = edge_attr[em];

    // gather Pa[ir], Pb[ic]: each lane 4+4 uint4 at sigma dwords q*4 + j*16
    uint4 pa[4], pb[4];
    #pragma unroll
    for (int j = 0; j < 4; ++j) {
        pa[j] = *(const uint4*)(Pa + (size_t)ir * 64 + q * 4 + j * 16);
        pb[j] = *(const uint4*)(Pb + (size_t)ic * 64 + q * 4 + j * 16);
    }

    // fuse: x1 = silu(Pa + Pb + ea*W1row256) -> A-fragments in registers
    const float* W1r = W1 + 256 * HID;
    union { uint4 u; s16x8 s; } afr[4];
    #pragma unroll
    for (int j = 0; j < 4; ++j) {
        // dword d = j*16 + q*4 + i  ->  col_lo = 32*j + q*4 + i, col_hi = +16
        float4 wlo = *(const float4*)(W1r + 32 * j + q * 4);
        float4 whi = *(const float4*)(W1r + 32 * j + q * 4 + 16);
        afr[j].u.x = fuse_silu_pack(pa[j].x, pb[j].x, ea, wlo.x, whi.x);
        afr[j].u.y = fuse_silu_pack(pa[j].y, pb[j].y, ea, wlo.y, whi.y);
        afr[j].u.z = fuse_silu_pack(pa[j].z, pb[j].z, ea, wlo.z, whi.z);
        afr[j].u.w = fuse_silu_pack(pa[j].w, pb[j].w, ea, wlo.w, whi.w);
    }

    // layer 2: [16 edges x 128] @ W2p (sigma-K), full N=128 per wave, B from L1
    f32x4 acc[8];
    #pragma unroll
    for (int nt = 0; nt < 8; ++nt) acc[nt] = f32x4{0.f, 0.f, 0.f, 0.f};
    #pragma unroll
    for (int ks = 0; ks < 4; ++ks) {
        #pragma unroll
        for (int nt = 0; nt < 8; ++nt) {
            s16x8 bf = *(const s16x8*)(W2p + (size_t)((ks * 4 + q) * HID + nt * 16 + c16) * 8);
            acc[nt] = __builtin_amdgcn_mfma_f32_16x16x32_bf16(afr[ks].s, bf, acc[nt], 0, 0, 0);
        }
    }

    // layer 3: phi[row] = sum_n silu(x2+b2)*W3 ; C-layout row = q*4+r, col = nt*16+c16
    float pr[4] = {0.f, 0.f, 0.f, 0.f};
    #pragma unroll
    for (int nt = 0; nt < 8; ++nt) {
        #pragma unroll
        for (int r = 0; r < 4; ++r) {
            float s = silu_f(acc[nt][r] + b2v[nt]);
            pr[r] = fmaf(s, w3v[nt], pr[r]);
        }
    }
    #pragma unroll
    for (int off = 8; off >= 1; off >>= 1) {
        #pragma unroll
        for (int r = 0; r < 4; ++r) pr[r] += __shfl_xor(pr[r], off);
    }

    // epilogue: lanes c16<4 each own edge e0 + q*4 + c16
    if (c16 < 4) {
        float v = pr[0];
        if (c16 == 1) v = pr[1];
        if (c16 == 2) v = pr[2];
        if (c16 == 3) v = pr[3];
        int e = e0 + q * 4 + c16;
        float scale = v * edge_mask[e];
        int r = edge_index[e];
        atomicAdd(&agg[r * 3 + 0], coord_diff[e * 3 + 0] * scale);
        atomicAdd(&agg[r * 3 + 1], coord_diff[e * 3 + 1] * scale);
        atomicAdd(&agg[r * 3 + 2], coord_diff[e * 3 + 2] * scale);
    }
}

__global__ void finalize_kernel(const float* __restrict__ coord,
                                const float* __restrict__ node_mask,
                                float* __restrict__ out) {
    int i = blockIdx.x * blockDim.x + threadIdx.x;
    if (i < NN) {
        float nm = node_mask[i];
        float a0 = out[i*3+0], a1 = out[i*3+1], a2 = out[i*3+2];
        out[i*3+0] = (coord[i*3+0] + a0 * 0.01f) * nm;
        out[i*3+1] = (coord[i*3+1] + a1 * 0.01f) * nm;
        out[i*3+2] = (coord[i*3+2] + a2 * 0.01f) * nm;
    }
}

extern "C" void kernel_launch(void* const* d_in, const int* in_sizes, int n_in,
                              void* d_out, int out_size, void* d_ws, size_t ws_size,
                              hipStream_t stream) {
    const float* h          = (const float*)d_in[0];
    const float* coord      = (const float*)d_in[1];
    const int*   edge_index = (const int*)d_in[2];
    const float* coord_diff = (const float*)d_in[3];
    const float* edge_attr  = (const float*)d_in[5];
    const float* node_mask  = (const float*)d_in[6];
    const float* edge_mask  = (const float*)d_in[7];
    const float* W1         = (const float*)d_in[8];
    const float* b1         = (const float*)d_in[9];
    const float* W2         = (const float*)d_in[10];
    const float* b2         = (const float*)d_in[11];
    const float* W3         = (const float*)d_in[12];
    float* out = (float*)d_out;

    const size_t nW1 = 32 * 128 * 8;   // shorts
    const size_t nW2 = 16 * 128 * 8;
    unsigned short* W1p = (unsigned short*)d_ws;
    unsigned short* W2p = W1p + nW1;
    u32* Pa = (u32*)(W2p + nW2);
    u32* Pb = Pa + (size_t)NN * 64;    // total ~25.7 MB (ws sufficiency proven in R4)

    const int out_q = out_size / 4;    // 150000/4 = 37500 float4s
    int prep_items = (int)(nW1 + nW2) + out_q;
    prep_full<<<(prep_items + 255) / 256, 256, 0, stream>>>(W1, W2, W1p, W2p,
                                                            (float4*)d_out, out_q);
    node_gemm<<<(NN + 63) / 64, 256, 0, stream>>>(h, W1p, b1, Pa, Pb);
    edge_main<<<NE / 64, 256, 0, stream>>>(Pa, Pb, edge_index, coord_diff, edge_attr,
                                           edge_mask, W2p, W1, b2, W3, out);
    finalize_kernel<<<(NN + 255) / 256, 256, 0, stream>>>(coord, node_mask, out);
}